// Round 5
// baseline (257.303 us; speedup 1.0000x reference)
//
#include <hip/hip_runtime.h>

// CRF forward partition, MI355X. B=1024, L=512, T=52.
//
// R11 = R10 (fwd/bwd chains on 2 waves, pk_fma matvec) + LDS-traffic halving.
// R10 evidence: 419 cyc/step-slot with only ~153 VALU-busy cyc; 26 broadcast
// ds_read_b128/step-slot x 16 cyc (1024B delivered each, 64 B/cyc/SIMD share
// of the CU's 256 B/clk LDS return bus) = 416 ~= 419 => LDS-BW-bound.
// Fix: lane-half h reads only 7 of 14 quads (h=0: quads 0-6, h=1: 7-13,
// quad 13 = zero pad), then v_permlane32_swap_b32 self-swaps rebroadcast
// each component: swap(x,x) -> {[x.lo|x.lo], [x.hi|x.hi]} both wave-uniform.
// 13 reads -> 7 reads (+28 VALU swaps); matvec bitwise identical to R10.
//
//   fwd:  u  = M_256...M_1 p0          (t = 1..256,   p'[j] = ef[j]*sum_i E[i][j] p[i])
//   bwd:  w <- E (ef_t (*) w)          (t = 511..257, w'[j] = sum_i E[j][i] ef[i] w[i])
//   out:  log(sum_j w[j]*u[j]) + shiftF + shiftB     (masked step = identity)

#define TT 52       // TAG_SIZE
#define LL 512      // sequence length
#define NS 8        // steps per group; normalize once per group
#define KSPLIT 256  // fwd covers t=1..KSPLIT; bwd covers t=KSPLIT+1..511

typedef float v2f __attribute__((ext_vector_type(2)));

__device__ __forceinline__ v2f pkfma(v2f a, v2f b, v2f c) {
#if __has_builtin(__builtin_elementwise_fma)
    return __builtin_elementwise_fma(a, b, c);   // lowers to v_pk_fma_f32
#else
    v2f r; r.x = fmaf(a.x, b.x, c.x); r.y = fmaf(a.y, b.y, c.y); return r;
#endif
}

__device__ __forceinline__ float rl(float x, int lane) {
    return __int_as_float(__builtin_amdgcn_readlane(__float_as_int(x), lane));
}

// Self-swap broadcast: from x (lanes 0-31 hold value A, lanes 32-63 hold B),
// produce lo = A in ALL lanes, hi = B in ALL lanes. One v_permlane32_swap_b32.
#if __has_builtin(__builtin_amdgcn_permlane32_swap)
typedef unsigned int uv2 __attribute__((ext_vector_type(2)));
__device__ __forceinline__ void bchalf(float x, float& lo, float& hi) {
    uv2 r = __builtin_amdgcn_permlane32_swap(__float_as_uint(x),
                                             __float_as_uint(x), false, false);
    lo = __uint_as_float(r.x);   // [x.lo | x.lo]
    hi = __uint_as_float(r.y);   // [x.hi | x.hi]
}
#else
__device__ __forceinline__ void bchalf(float x, float& lo, float& hi) {
    float a = x, b = x;
    asm volatile("v_permlane32_swap_b32 %0, %1" : "+v"(a), "+v"(b));
    lo = a; hi = b;
}
#endif

// Split-read matvec: lane-half h reads quads (7h .. 7h+6) from pq, self-swaps
// rebroadcast to uniform quads P[0..12] (quad 13 = pad zeros, dropped), then
// the R10 pkfma reduction. Returns sum_i E[i]*p[i].
__device__ __forceinline__ float matvec52s(const float4* pq, int h, const v2f* E2) {
    float4 A[7];
#pragma unroll
    for (int k = 0; k < 7; ++k) A[k] = pq[k + 7 * h];
    float4 P[13];
#pragma unroll
    for (int k = 0; k < 6; ++k) {
        const float* a = (const float*)(A + k);
        float* pl = (float*)(P + k);
        float* ph = (float*)(P + k + 7);
#pragma unroll
        for (int c = 0; c < 4; ++c) bchalf(a[c], pl[c], ph[c]);
    }
    {
        const float* a = (const float*)(A + 6);
        float* pl = (float*)(P + 6);
#pragma unroll
        for (int c = 0; c < 4; ++c) { float d_; bchalf(a[c], pl[c], d_); }
    }
    v2f ae0 = {0.f, 0.f}, ae1 = {0.f, 0.f};
    v2f ao0 = {0.f, 0.f}, ao1 = {0.f, 0.f};
#pragma unroll
    for (int kq = 0; kq < TT / 4; ++kq) {
        float4 q = P[kq];
        v2f lo = {q.x, q.y};
        v2f hi = {q.z, q.w};
        if ((kq & 1) == 0) {
            ae0 = pkfma(lo, E2[2 * kq + 0], ae0);
            ae1 = pkfma(hi, E2[2 * kq + 1], ae1);
        } else {
            ao0 = pkfma(lo, E2[2 * kq + 0], ao0);
            ao1 = pkfma(hi, E2[2 * kq + 1], ao1);
        }
    }
    v2f s = (ae0 + ao0) + (ae1 + ao1);
    return s.x + s.y;
}

__global__ void __launch_bounds__(128)
__attribute__((amdgpu_waves_per_eu(2, 2)))
crf_fwd(
    const float* __restrict__ feats,   // (B, L, T)
    const int*   __restrict__ mask,    // (B, L)
    const float* __restrict__ trans,   // (T, T)
    float*       __restrict__ out)     // scalar accumulator (pre-zeroed)
{
    __shared__ __align__(16) float plds[2][64];  // per-wave broadcast buffers
    __shared__ float shsh[2];                    // per-wave shift handoff

    const int b   = blockIdx.x;
    const int tid = threadIdx.x;
    const int w   = tid >> 6;           // 0 = fwd wave, 1 = bwd wave
    const int j   = tid & 63;           // lane = tag
    const int h   = j >> 5;             // lane half (read-split index)
    const bool act = (j < TT);
    const int jc = act ? j : 0;         // clamped index for safe loads

    const float* fb = feats + (size_t)b * LL * TT;
    const int*   mb = mask  + (size_t)b * LL;

    float pv;      // this wave's state vector entry (p[j] fwd / w[j] bwd)
    float shift;   // log of accumulated normalization factors

    if (w == 0) {
        // ---------------- forward chain: t = 1 .. 256 ----------------
        // E column j packed: E2[k] = {exp(trans[2k][j]), exp(trans[2k+1][j])}.
        v2f E2[TT / 2];
#pragma unroll
        for (int k = 0; k < TT / 2; ++k) {
            float e0 = __expf(trans[(2 * k + 0) * TT + jc]);
            float e1 = __expf(trans[(2 * k + 1) * TT + jc]);
            E2[k].x = act ? e0 : 0.0f;
            E2[k].y = act ? e1 : 0.0f;
        }

        // t=0 init: part0[j] = feats[b,0,j] + trans[START][j]; normalize.
        float part0 = act ? (fb[j] + trans[(TT - 2) * TT + j]) : -1.0e30f;
        shift = rl(part0, 0);
        pv = act ? __expf(part0 - shift) : 0.0f;
        plds[0][j] = pv;                 // lanes >= TT keep pad zeros

        const float4* pq = (const float4*)plds[0];

        float fA[NS], fB[NS]; int mA[NS], mB[NS];
#pragma unroll
        for (int u = 0; u < NS; ++u) {
            fA[u] = fb[(1 + u) * TT + jc];
            mA[u] = mb[1 + u];
        }

        // Group body: consume fp/mc, prefetch next group into fn/mn.
        auto fwd_group = [&](float (&fp)[NS], int (&mc)[NS],
                             float (&fn)[NS], int (&mn)[NS], int t0) {
#pragma unroll
            for (int u = 0; u < NS; ++u) {
                int tn = t0 + NS + u;            // <= 264 < LL, in-bounds
                fn[u] = fb[tn * TT + jc];
                mn[u] = mb[tn];
            }
            float ef[NS];
#pragma unroll
            for (int u = 0; u < NS; ++u) ef[u] = __expf(fp[u]);
#pragma unroll
            for (int u = 0; u < NS; ++u) {
                float pn = matvec52s(pq, h, E2) * ef[u];
                pv = (mc[u] > 0) ? pn : pv;      // branchless mask select
                if (u == NS - 1) {
                    float c = rl(pv, 0);
                    shift += __logf(c);
                    pv *= __builtin_amdgcn_rcpf(c);
                }
                plds[0][j] = pv;                 // broadcast for next step
            }
        };

        // 32 groups (t0 = 1..249) as 16 ping-pong pairs: t = 1..256 exactly.
        for (int t0 = 1; t0 <= 241; t0 += 2 * NS) {
            fwd_group(fA, mA, fB, mB, t0);
            fwd_group(fB, mB, fA, mA, t0 + NS);
        }
    } else {
        // ---------------- backward chain: t = 511 .. 257 ----------------
        // E row j packed: E2[k] = {exp(trans[j][2k]), exp(trans[j][2k+1])}.
        v2f E2[TT / 2];
#pragma unroll
        for (int k = 0; k < TT / 2; ++k) {
            float e0 = __expf(trans[jc * TT + 2 * k + 0]);
            float e1 = __expf(trans[jc * TT + 2 * k + 1]);
            E2[k].x = act ? e0 : 0.0f;
            E2[k].y = act ? e1 : 0.0f;
        }

        // init: w[j] = exp(trans[j][END])
        pv = act ? __expf(trans[jc * TT + (TT - 1)]) : 0.0f;
        shift = 0.0f;

        const float4* pq = (const float4*)plds[1];

        // k = 0..254 maps to t = 511-k (t = 511..257).
        float fA[NS], fB[NS]; int mA[NS], mB[NS];
#pragma unroll
        for (int u = 0; u < NS; ++u) {
            fA[u] = fb[(LL - 1 - u) * TT + jc];
            mA[u] = mb[LL - 1 - u];
        }

        auto bwd_group = [&](float (&fp)[NS], int (&mc)[NS],
                             float (&fn)[NS], int (&mn)[NS], int g) {
#pragma unroll
            for (int u = 0; u < NS; ++u) {
                int kn = g + NS + u;             // <= 255 -> t >= 256, in-bounds
                fn[u] = fb[(LL - 1 - kn) * TT + jc];
                mn[u] = mb[LL - 1 - kn];
            }
            float ef[NS];
#pragma unroll
            for (int u = 0; u < NS; ++u) ef[u] = __expf(fp[u]);
#pragma unroll
            for (int u = 0; u < NS; ++u) {
                plds[1][j] = ef[u] * pv;         // broadcast ef (*) w (pad stays 0)
                float pn = matvec52s(pq, h, E2);
                pv = (mc[u] > 0) ? pn : pv;      // branchless mask select
                if (u == NS - 1) {
                    float c = rl(pv, 0);
                    shift += __logf(c);
                    pv *= __builtin_amdgcn_rcpf(c);
                }
            }
        };

        // 30 groups as 15 ping-pong pairs (k = 0..239), 1 single group
        // (k = 240..247, prefetches k = 248..255 into fB), then 7-step tail.
        for (int g = 0; g <= 224; g += 2 * NS) {
            bwd_group(fA, mA, fB, mB, g);
            bwd_group(fB, mB, fA, mA, g + NS);
        }
        bwd_group(fA, mA, fB, mB, 240);

        // Tail: 7 steps, k = 248..254 (data in fB[0..6]).
#pragma unroll
        for (int u = 0; u < 7; ++u) {
            float efu = __expf(fB[u]);
            plds[1][j] = efu * pv;
            float pn = matvec52s(pq, h, E2);
            pv = (mB[u] > 0) ? pn : pv;
        }

        // Final safety normalize (bounds w away from inf before combine).
        {
            float c = rl(pv, 0);
            shift += __logf(c);
            pv *= __builtin_amdgcn_rcpf(c);
        }
    }

    // ---------------- combine: S = log(sum_j w[j]*u[j]) + shiftF + shiftB ----
    plds[w][j] = pv;
    if (j == 0) shsh[w] = shift;
    __syncthreads();

    if (w == 0) {
        float wj  = plds[1][j];                  // bwd vector (0 for j >= TT)
        float val = act ? (pv * wj) : 0.0f;
#pragma unroll
        for (int o = 32; o >= 1; o >>= 1)
            val += __shfl_xor(val, o, 64);
        if (j == 0) atomicAdd(out, __logf(val) + shift + shsh[1]);
    }
}

extern "C" void kernel_launch(void* const* d_in, const int* in_sizes, int n_in,
                              void* d_out, int out_size, void* d_ws, size_t ws_size,
                              hipStream_t stream) {
    const float* feats = (const float*)d_in[0];
    const int*   mask  = (const int*)d_in[1];
    const float* trans = (const float*)d_in[2];
    float* out = (float*)d_out;

    const int B = in_sizes[1] / LL;   // mask is (B, L)

    hipMemsetAsync(d_out, 0, sizeof(float), stream);
    crf_fwd<<<B, 128, 0, stream>>>(feats, mask, trans, out);
}

// Round 6
// 200.590 us; speedup vs baseline: 1.2827x; 1.2827x over previous
//
#include <hip/hip_runtime.h>

// CRF forward partition, MI355X. B=1024, L=512, T=52.
//
// R12 = R10 (fwd/bwd chains on 2 waves, pk_fma matvec) + half-split dot
// product. R10/R11 evidence: R10 is LDS-return-BW-bound (8 waves/CU x 13
// ds_read_b128 x 1024B = 416 cyc/step at 256 B/cyc/CU ~= 419 observed);
// R11's full rebroadcast (28 permlane swaps) tripled VALU. Fix: DON'T
// rebroadcast. Lane half h reads only its 7 quads (p[28h..28h+27]); lane j
// accumulates P1 = partial for own column j and P2 = partial for partner
// column j^32, both over its i-half; ONE permlane32_swap + select brings the
// partner's P2 = the other i-half of column j. p'[j] = P1 + X.
//   LDS: 13 -> 7 reads/wave-step (224 cyc/CU floor). VALU: ~100 cyc/wave-step.
// permlane32_swap self-swap semantics verified by R11 (absmax 0.0):
//   r.x = [v.lo|v.lo], r.y = [v.hi|v.hi].
// Lanes 52..63 carry the i>=28 partials for columns 20..31 (their own
// outputs are exact 0 via zero coefficient guards -> pad invariant holds).
//
//   fwd:  u  = M_256...M_1 p0          (t = 1..256,   p'[j] = ef[j]*sum_i E[i][j] p[i])
//   bwd:  w <- E (ef_t (*) w)          (t = 511..257, w'[j] = sum_i E[j][i] ef[i] w[i])
//   out:  log(sum_j w[j]*u[j]) + shiftF + shiftB     (masked step = identity)

#define TT 52       // TAG_SIZE
#define LL 512      // sequence length
#define NS 8        // steps per group; normalize once per group

typedef float v2f __attribute__((ext_vector_type(2)));
typedef unsigned int uv2 __attribute__((ext_vector_type(2)));

__device__ __forceinline__ v2f pkfma(v2f a, v2f b, v2f c) {
#if __has_builtin(__builtin_elementwise_fma)
    return __builtin_elementwise_fma(a, b, c);   // lowers to v_pk_fma_f32
#else
    v2f r; r.x = fmaf(a.x, b.x, c.x); r.y = fmaf(a.y, b.y, c.y); return r;
#endif
}

__device__ __forceinline__ float rl(float x, int lane) {
    return __int_as_float(__builtin_amdgcn_readlane(__float_as_int(x), lane));
}

// Cross-half exchange: X[lane] = v[lane ^ 32]. One swap + one select.
__device__ __forceinline__ float xhalf(float v, bool hlo) {
#if __has_builtin(__builtin_amdgcn_permlane32_swap)
    uv2 r = __builtin_amdgcn_permlane32_swap(__float_as_uint(v),
                                             __float_as_uint(v), false, false);
    // r.x = [v.lo|v.lo], r.y = [v.hi|v.hi]   (verified: R11 absmax 0.0)
    return hlo ? __uint_as_float(r.y) : __uint_as_float(r.x);
#else
    return __shfl_xor(v, 32, 64);
#endif
}

// Half-split matvec. pqh = this half's 7 quads (p[28h .. 28h+27]).
// Ea[k]/Eb[k] pack coefficients for own column j / partner column j^32 over
// i' = 2k, 2k+1 (i = 28h + i'). Returns full sum_i E[i]*p[i] for column j.
__device__ __forceinline__ float matvec52h(const float4* pqh, const v2f* Ea,
                                           const v2f* Eb, bool hlo) {
    v2f a0 = {0.f, 0.f}, a1 = {0.f, 0.f};   // own column (2 chains of 7)
    v2f b0 = {0.f, 0.f}, b1 = {0.f, 0.f};   // partner column
#pragma unroll
    for (int q = 0; q < 7; ++q) {
        float4 Q = pqh[q];
        v2f lo = {Q.x, Q.y};
        v2f hi = {Q.z, Q.w};
        a0 = pkfma(lo, Ea[2 * q + 0], a0);
        a1 = pkfma(hi, Ea[2 * q + 1], a1);
        b0 = pkfma(lo, Eb[2 * q + 0], b0);
        b1 = pkfma(hi, Eb[2 * q + 1], b1);
    }
    v2f s1 = a0 + a1;
    v2f s2 = b0 + b1;
    float P1 = s1.x + s1.y;
    float P2 = s2.x + s2.y;
    return P1 + xhalf(P2, hlo);
}

__global__ void __launch_bounds__(128)
__attribute__((amdgpu_waves_per_eu(2, 2)))
crf_fwd(
    const float* __restrict__ feats,   // (B, L, T)
    const int*   __restrict__ mask,    // (B, L)
    const float* __restrict__ trans,   // (T, T)
    float*       __restrict__ out)     // scalar accumulator (pre-zeroed)
{
    __shared__ __align__(16) float plds[2][64];  // per-wave broadcast buffers
    __shared__ float shsh[2];                    // per-wave shift handoff

    const int b   = blockIdx.x;
    const int tid = threadIdx.x;
    const int w   = tid >> 6;           // 0 = fwd wave, 1 = bwd wave
    const int j   = tid & 63;           // lane = tag (column owner)
    const int h   = j >> 5;             // lane half
    const bool hlo = (h == 0);
    const int jx  = j ^ 32;             // partner column
    const int i0  = 28 * h;             // this half's i-range start
    const bool act = (j < TT);
    const int jc = act ? j : 0;         // clamped index for safe loads

    const float* fb = feats + (size_t)b * LL * TT;
    const int*   mb = mask  + (size_t)b * LL;

    float pv;      // this wave's state vector entry (p[j] fwd / w[j] bwd)
    float shift;   // log of accumulated normalization factors

    // Coefficient packs: Ea = own column j, Eb = partner column jx, over
    // i = i0 .. i0+27. coef(i,c) = exp(trans[i][c]) fwd / exp(trans[c][i]) bwd,
    // zero when i >= TT or c >= TT (clamped loads, zero-selected).
    v2f Ea[14], Eb[14];
    if (w == 0) {
#pragma unroll
        for (int k = 0; k < 14; ++k) {
            int ia = i0 + 2 * k, ib = ia + 1;
            int iac = ia < TT ? ia : 0, ibc = ib < TT ? ib : 0;
            int jcc = jc, jxc = jx < TT ? jx : 0;
            float eax = __expf(trans[iac * TT + jcc]);
            float eay = __expf(trans[ibc * TT + jcc]);
            float ebx = __expf(trans[iac * TT + jxc]);
            float eby = __expf(trans[ibc * TT + jxc]);
            Ea[k].x = (ia < TT && j  < TT) ? eax : 0.0f;
            Ea[k].y = (ib < TT && j  < TT) ? eay : 0.0f;
            Eb[k].x = (ia < TT && jx < TT) ? ebx : 0.0f;
            Eb[k].y = (ib < TT && jx < TT) ? eby : 0.0f;
        }
    } else {
#pragma unroll
        for (int k = 0; k < 14; ++k) {
            int ia = i0 + 2 * k, ib = ia + 1;
            int iac = ia < TT ? ia : 0, ibc = ib < TT ? ib : 0;
            int jcc = jc, jxc = jx < TT ? jx : 0;
            float eax = __expf(trans[jcc * TT + iac]);
            float eay = __expf(trans[jcc * TT + ibc]);
            float ebx = __expf(trans[jxc * TT + iac]);
            float eby = __expf(trans[jxc * TT + ibc]);
            Ea[k].x = (ia < TT && j  < TT) ? eax : 0.0f;
            Ea[k].y = (ib < TT && j  < TT) ? eay : 0.0f;
            Eb[k].x = (ia < TT && jx < TT) ? ebx : 0.0f;
            Eb[k].y = (ib < TT && jx < TT) ? eby : 0.0f;
        }
    }

    const float4* pqh = ((const float4*)plds[w]) + 7 * h;  // this half's quads

    if (w == 0) {
        // ---------------- forward chain: t = 1 .. 256 ----------------
        // t=0 init: part0[j] = feats[b,0,j] + trans[START][j]; normalize.
        float part0 = act ? (fb[j] + trans[(TT - 2) * TT + j]) : -1.0e30f;
        shift = rl(part0, 0);
        pv = act ? __expf(part0 - shift) : 0.0f;
        plds[0][j] = pv;                 // lanes >= TT write pad zeros

        float fA[NS], fB[NS]; int mA[NS], mB[NS];
#pragma unroll
        for (int u = 0; u < NS; ++u) {
            fA[u] = fb[(1 + u) * TT + jc];
            mA[u] = mb[1 + u];
        }

        auto fwd_group = [&](float (&fp)[NS], int (&mc)[NS],
                             float (&fn)[NS], int (&mn)[NS], int t0) {
#pragma unroll
            for (int u = 0; u < NS; ++u) {
                int tn = t0 + NS + u;            // <= 264 < LL, in-bounds
                fn[u] = fb[tn * TT + jc];
                mn[u] = mb[tn];
            }
            float ef[NS];
#pragma unroll
            for (int u = 0; u < NS; ++u) ef[u] = __expf(fp[u]);
#pragma unroll
            for (int u = 0; u < NS; ++u) {
                float pn = matvec52h(pqh, Ea, Eb, hlo) * ef[u];
                pv = (mc[u] > 0) ? pn : pv;      // branchless mask select
                if (u == NS - 1) {
                    float c = rl(pv, 0);
                    shift += __logf(c);
                    pv *= __builtin_amdgcn_rcpf(c);
                }
                plds[0][j] = pv;                 // broadcast for next step
            }
        };

        // 32 groups (t0 = 1..249) as 16 ping-pong pairs: t = 1..256 exactly.
        for (int t0 = 1; t0 <= 241; t0 += 2 * NS) {
            fwd_group(fA, mA, fB, mB, t0);
            fwd_group(fB, mB, fA, mA, t0 + NS);
        }
    } else {
        // ---------------- backward chain: t = 511 .. 257 ----------------
        // init: w[j] = exp(trans[j][END])
        pv = act ? __expf(trans[jc * TT + (TT - 1)]) : 0.0f;
        shift = 0.0f;

        // k = 0..254 maps to t = 511-k (t = 511..257).
        float fA[NS], fB[NS]; int mA[NS], mB[NS];
#pragma unroll
        for (int u = 0; u < NS; ++u) {
            fA[u] = fb[(LL - 1 - u) * TT + jc];
            mA[u] = mb[LL - 1 - u];
        }

        auto bwd_group = [&](float (&fp)[NS], int (&mc)[NS],
                             float (&fn)[NS], int (&mn)[NS], int g) {
#pragma unroll
            for (int u = 0; u < NS; ++u) {
                int kn = g + NS + u;             // <= 255 -> t >= 256, in-bounds
                fn[u] = fb[(LL - 1 - kn) * TT + jc];
                mn[u] = mb[LL - 1 - kn];
            }
            float ef[NS];
#pragma unroll
            for (int u = 0; u < NS; ++u) ef[u] = __expf(fp[u]);
#pragma unroll
            for (int u = 0; u < NS; ++u) {
                plds[1][j] = ef[u] * pv;         // broadcast ef (*) w (pads 0)
                float pn = matvec52h(pqh, Ea, Eb, hlo);
                pv = (mc[u] > 0) ? pn : pv;      // branchless mask select
                if (u == NS - 1) {
                    float c = rl(pv, 0);
                    shift += __logf(c);
                    pv *= __builtin_amdgcn_rcpf(c);
                }
            }
        };

        // 30 groups as 15 ping-pong pairs (k = 0..239), 1 single group
        // (k = 240..247, prefetches k = 248..255 into fB), then 7-step tail.
        for (int g = 0; g <= 224; g += 2 * NS) {
            bwd_group(fA, mA, fB, mB, g);
            bwd_group(fB, mB, fA, mA, g + NS);
        }
        bwd_group(fA, mA, fB, mB, 240);

        // Tail: 7 steps, k = 248..254 (data in fB[0..6]).
#pragma unroll
        for (int u = 0; u < 7; ++u) {
            float efu = __expf(fB[u]);
            plds[1][j] = efu * pv;
            float pn = matvec52h(pqh, Ea, Eb, hlo);
            pv = (mB[u] > 0) ? pn : pv;
        }

        // Final safety normalize (bounds w away from inf before combine).
        {
            float c = rl(pv, 0);
            shift += __logf(c);
            pv *= __builtin_amdgcn_rcpf(c);
        }
    }

    // ---------------- combine: S = log(sum_j w[j]*u[j]) + shiftF + shiftB ----
    plds[w][j] = pv;
    if (j == 0) shsh[w] = shift;
    __syncthreads();

    if (w == 0) {
        float wj  = plds[1][j];                  // bwd vector (0 for j >= TT)
        float val = act ? (pv * wj) : 0.0f;
#pragma unroll
        for (int o = 32; o >= 1; o >>= 1)
            val += __shfl_xor(val, o, 64);
        if (j == 0) atomicAdd(out, __logf(val) + shift + shsh[1]);
    }
}

extern "C" void kernel_launch(void* const* d_in, const int* in_sizes, int n_in,
                              void* d_out, int out_size, void* d_ws, size_t ws_size,
                              hipStream_t stream) {
    const float* feats = (const float*)d_in[0];
    const int*   mask  = (const int*)d_in[1];
    const float* trans = (const float*)d_in[2];
    float* out = (float*)d_out;

    const int B = in_sizes[1] / LL;   // mask is (B, L)

    hipMemsetAsync(d_out, 0, sizeof(float), stream);
    crf_fwd<<<B, 128, 0, stream>>>(feats, mask, trans, out);
}